// Round 19
// baseline (1373.122 us; speedup 1.0000x reference)
//
#include <hip/hip_runtime.h>

typedef unsigned short u16;
typedef unsigned int u32;
typedef _Float16 f16;
typedef __attribute__((ext_vector_type(8))) _Float16 f16x8;
typedef __attribute__((ext_vector_type(4))) _Float16 f16x4;
typedef __attribute__((ext_vector_type(4))) float f32x4;

#define NN 40000
#define EE 100000
#define DD 64
#define BB 256
#define XTS 136  // s_xT stride (f16): 272B rows, 16B-aligned
#define EPB 128  // edges per block; 8 waves = 4 edge-groups x 2 col-pairs

__device__ inline float sigmoidf_(float x){
    return 1.f / (1.f + __expf(-x));
}
__device__ inline float tanhf_(float x){
    x = fmaxf(fminf(x, 15.f), -15.f);
    float e = __expf(2.f * x);
    return (e - 1.f) / (e + 1.f);
}

typedef __attribute__((address_space(3))) unsigned int lds_u32;
typedef __attribute__((address_space(1))) const unsigned int g_u32;
__device__ inline void gload_lds16(const void* g, void* l){
    __builtin_amdgcn_global_load_lds((g_u32*)g, (lds_u32*)l, 16, 0, 0);
}

// ---------------- prep: converts, transposes, eff bias, offsets --------------
__global__ __launch_bounds__(256) void prep_kernel(
    const float* __restrict__ en_w2, f16* __restrict__ w2h,
    const float* __restrict__ gru_wih, const float* __restrict__ gru_whh,
    f16* __restrict__ wf16h, f16* __restrict__ wf16l,
    const float* __restrict__ ls_wih0, const float* __restrict__ ls_wih12,
    const float* __restrict__ ls_whh, float* __restrict__ lsT,
    const float* __restrict__ lin3_w, float* __restrict__ lin3T,
    const float* __restrict__ gru_bih, const float* __restrict__ conv_b,
    float* __restrict__ effb,
    const int* __restrict__ node_graph, int* __restrict__ offs)
{
    int i = blockIdx.x * 256 + threadIdx.x;
    if (i < 524288){
        w2h[i] = (f16)en_w2[i];
        return;
    }
    i -= 524288;
    if (i < 49152){                       // GRU weights -> f16 hi/lo, [gg][g][d]
        int sel = i / 12288;              // 0:ih-hi 1:ih-lo 2:hh-hi 3:hh-lo
        int r = i % 12288;
        int gg = sel >> 1, islo = sel & 1;
        float v = (gg ? gru_whh : gru_wih)[r];
        f16 hi = (f16)v;
        if (islo) wf16l[gg * 12288 + r] = (f16)(v - (float)hi);
        else      wf16h[gg * 12288 + r] = hi;
        return;
    }
    i -= 49152;
    if (i < 114688){
        float v;
        if (i < 32768){
            int d = i >> 8, g = i & 255;
            v = ls_wih0[g * 128 + d];
        } else if (i < 65536){
            int j = i - 32768;
            int l = j >> 14, r = j & 16383;
            int d = r >> 8, g = r & 255;
            v = ls_wih12[l * 16384 + g * 64 + d];
        } else {
            int j = i - 65536;
            int l = j >> 14, r = j & 16383;
            int d = r >> 8, g = r & 255;
            v = ls_whh[l * 16384 + g * 64 + d];
        }
        lsT[i] = v;
        return;
    }
    i -= 114688;
    if (i < 16384){
        int ii = i >> 7, jj = i & 127;
        lin3T[i] = lin3_w[jj * 128 + ii];
        return;
    }
    i -= 16384;
    if (i < 192){
        float b = gru_bih[i];
        #pragma unroll
        for (int d = 0; d < 64; d++) b += gru_wih[i * 64 + d] * conv_b[d];
        effb[i] = b;
        return;
    }
    i -= 192;
    if (i <= 256){
        int lo = 0, hi = NN;
        while (lo < hi){
            int mid = (lo + hi) >> 1;
            if (node_graph[mid] < i) lo = mid + 1; else hi = mid;
        }
        offs[i] = lo;
        return;
    }
}

// ---------------- lin0: out = n_feat @ lin0_w^T + b  (writes h in d_out) -----
__global__ __launch_bounds__(256) void lin0_kernel(
    const float* __restrict__ nf, const float* __restrict__ w,
    const float* __restrict__ b, float* __restrict__ out)
{
    int tid = blockIdx.x * 256 + threadIdx.x;
    int n = tid >> 6, d = tid & 63;
    if (n >= NN) return;
    float acc = b[d];
    const float* nr = nf + (size_t)n * 23;
    const float* wr = w + d * 23;
    #pragma unroll
    for (int j = 0; j < 23; j++) acc = fmaf(nr[j], wr[j], acc);
    out[(size_t)n * 64 + d] = acc;
}

// ---------------- edge hidden: relu(e_feat @ w1^T + b1) -> f16 ---------------
__global__ __launch_bounds__(256) void edge_hidden_kernel(
    const float* __restrict__ ef, const float* __restrict__ w1,
    const float* __restrict__ b1, f16* __restrict__ hidh)
{
    int tid = blockIdx.x * 256 + threadIdx.x;
    int e = tid >> 7, k = tid & 127;
    if (e >= EE) return;
    float acc = b1[k];
    const float* er = ef + (size_t)e * 19;
    const float* wr = w1 + k * 19;
    #pragma unroll
    for (int j = 0; j < 19; j++) acc = fmaf(er[j], wr[j], acc);
    acc = fmaxf(acc, 0.f);
    hidh[(size_t)e * 128 + k] = (f16)acc;
}

// ---------------- fused msg: R18 structure, f16 s_xT -> 3 blocks/CU ----------
// msg[e,f] = sum_d x[e,d] * ( sum_k u[e,k]*W2[d*64+f,k] + b2[d*64+f] )
// block = 128 edges, 512 threads, 8 waves = (eg of 32 edges) x (fp col-pair).
// s_xT stored f16 (17.4 KB vs 33): LDS ~50 KB -> 3 blocks/CU = 24 waves/CU
// (vs 16) -- the barrier-drain stall pool shrinks ~1/waves. Error: adds the
// x-f16 source; budget 0.0217 + ~0.008 ~ 0.03 < 0.0394. B layout / DMA /
// sync byte-identical to R18 (proven 164us, 600K conflicts).
__global__ __launch_bounds__(512) void msg_fused_kernel(
    const float* __restrict__ h, const f16* __restrict__ hidh,
    const f16* __restrict__ w2h, const float* __restrict__ b2,
    const int* __restrict__ src, const int* __restrict__ dst,
    float* __restrict__ m)
{
    __shared__ f16 s_xT[64 * XTS];           // [d][el] transposed x, f16 (17.4 KB)
    __shared__ int s_dst[EPB];
    __shared__ f16x8 s_bb[2][1024];          // 2 x 16 KB B tiles

    const int t = threadIdx.x;
    const int base = blockIdx.x * EPB;
    const int lane = t & 63;
    const int wid = t >> 6;

    int goff[2], lbase[2];
    #pragma unroll
    for (int cc = 0; cc < 2; cc++){
        int s = cc * 512 + wid * 64 + lane;
        int kh = s >> 9;
        int c2 = s & 511;
        int col = c2 >> 3;
        int jj = (c2 & 7) ^ (col & 7);
        goff[cc] = col * 128 + kh * 64 + jj * 8;
        lbase[cc] = cc * 512 + wid * 64;
    }

#define STG_ISSUE(DN, BUF)                                                   \
    {                                                                        \
        const f16* gsrc = w2h + (size_t)(DN) * 8192;                         \
        gload_lds16(gsrc + goff[0], &s_bb[BUF][lbase[0]]);                   \
        gload_lds16(gsrc + goff[1], &s_bb[BUF][lbase[1]]);                   \
    }

    STG_ISSUE(0, 0);                         // DMA tile 0 while we stage x

    for (int i = t; i < EPB * 64; i += 512){
        int el = i >> 6, f = i & 63;
        int e = base + el;
        float v = 0.f;
        if (e < EE) v = h[(size_t)src[e] * 64 + f];
        s_xT[f * XTS + el] = (f16)v;
    }
    if (t < EPB){
        int e = base + t;
        s_dst[t] = (e < EE) ? dst[e] : -1;
    }

    const int eg = wid >> 1;                 // edge group: 32 edges
    const int fp = wid & 1;                  // col pair: cols fp*32..fp*32+31
    const int r16 = lane & 15;
    const int kg = lane >> 4;
    const int we = eg * 32;
    const int sw = r16 & 7;

    // A fragments, full K: 8 frags = 32 VGPR
    f16x8 ah[2][4];
    #pragma unroll
    for (int mt = 0; mt < 2; mt++){
        int e = base + we + mt * 16 + r16;
        #pragma unroll
        for (int ks = 0; ks < 4; ks++){
            if (e < EE){
                ah[mt][ks] = *(const f16x8*)(hidh + (size_t)e * 128 + ks * 32 + kg * 8);
            } else {
                f16x8 z = {0,0,0,0,0,0,0,0};
                ah[mt][ks] = z;
            }
        }
    }

    f32x4 msg[2][2];                         // [mt][ftl]: 16 VGPR
    #pragma unroll
    for (int a = 0; a < 2; a++)
        #pragma unroll
        for (int b = 0; b < 2; b++){
            f32x4 z = {0.f, 0.f, 0.f, 0.f};
            msg[a][b] = z;
        }

    int rslot[2][4];
    #pragma unroll
    for (int ftl = 0; ftl < 2; ftl++){
        int col = fp * 32 + ftl * 16 + r16;
        #pragma unroll
        for (int ks = 0; ks < 4; ks++){
            int j2 = (ks & 1) * 4 + kg;
            rslot[ftl][ks] = (ks >> 1) * 512 + col * 8 + (j2 ^ sw);
        }
    }

    __syncthreads();                         // tile 0 DMA + s_xT/s_dst complete

    for (int d = 0; d < 64; d++){
        int cur = d & 1;
        if (d < 63) STG_ISSUE(d + 1, cur ^ 1);   // async DMA next tile
        f32x4 xv[2];
        #pragma unroll
        for (int mt = 0; mt < 2; mt++){
            f16x4 xh = *(const f16x4*)&s_xT[d * XTS + we + mt * 16 + kg * 4];
            #pragma unroll
            for (int r = 0; r < 4; r++) xv[mt][r] = (float)xh[r];
        }
        __builtin_amdgcn_s_setprio(1);
        #pragma unroll
        for (int ftl = 0; ftl < 2; ftl++){
            f16x8 bf0 = s_bb[cur][rslot[ftl][0]];
            f16x8 bf1 = s_bb[cur][rslot[ftl][1]];
            f16x8 bf2 = s_bb[cur][rslot[ftl][2]];
            f16x8 bf3 = s_bb[cur][rslot[ftl][3]];
            float b2v = b2[d * 64 + fp * 32 + ftl * 16 + r16];
            #pragma unroll
            for (int mt = 0; mt < 2; mt++){
                f32x4 acc = {b2v, b2v, b2v, b2v};
                acc = __builtin_amdgcn_mfma_f32_16x16x32_f16(ah[mt][0], bf0, acc, 0, 0, 0);
                acc = __builtin_amdgcn_mfma_f32_16x16x32_f16(ah[mt][1], bf1, acc, 0, 0, 0);
                acc = __builtin_amdgcn_mfma_f32_16x16x32_f16(ah[mt][2], bf2, acc, 0, 0, 0);
                acc = __builtin_amdgcn_mfma_f32_16x16x32_f16(ah[mt][3], bf3, acc, 0, 0, 0);
                msg[mt][ftl] = xv[mt] * acc + msg[mt][ftl];
            }
        }
        __builtin_amdgcn_s_setprio(0);
        __syncthreads();                     // vmcnt drain -> next tile ready
    }
#undef STG_ISSUE

    // scatter-add: wave owns (eg edges) x (fp cols) -> each output added once
    #pragma unroll
    for (int mt = 0; mt < 2; mt++){
        #pragma unroll
        for (int r = 0; r < 4; r++){
            int el = we + mt * 16 + kg * 4 + r;
            int dt = s_dst[el];
            if (dt >= 0){
                #pragma unroll
                for (int ftl = 0; ftl < 2; ftl++)
                    atomicAdd(&m[(size_t)dt * 64 + fp * 32 + ftl * 16 + r16],
                              msg[mt][ftl][r]);
            }
        }
    }
}

// ---------------- GRU via MFMA: G = X @ W^T (3-mfma hi/lo), gate, h in-place -
__global__ __launch_bounds__(256) void gru_mfma_kernel(
    float* __restrict__ m, float* __restrict__ h,
    const f16* __restrict__ wf16h, const f16* __restrict__ wf16l,
    const float* __restrict__ effb, const float* __restrict__ bhh)
{
    __shared__ float s_g[2][32][194];
    const int t = threadIdx.x;
    const int base = blockIdx.x * 32;
    const int lane = t & 63;
    const int wid = t >> 6;
    const int rt = wid & 1;
    const int gg = wid >> 1;
    const int r16 = lane & 15;
    const int kg = lane >> 4;

    const float* __restrict__ X = gg ? h : m;
    int n = base + rt * 16 + r16;            // 40000 % 32 == 0 -> always valid

    f16x8 ah[2], al[2];
    #pragma unroll
    for (int ks = 0; ks < 2; ks++){
        const float* xp = X + (size_t)n * 64 + ks * 32 + kg * 8;
        f32x4 v0 = *(const f32x4*)(xp);
        f32x4 v1 = *(const f32x4*)(xp + 4);
        #pragma unroll
        for (int j = 0; j < 4; j++){
            f16 hi0 = (f16)v0[j], hi1 = (f16)v1[j];
            ah[ks][j] = hi0;     ah[ks][4 + j] = hi1;
            al[ks][j] = (f16)(v0[j] - (float)hi0);
            al[ks][4 + j] = (f16)(v1[j] - (float)hi1);
        }
    }

    const f16* __restrict__ wh = wf16h + gg * 12288;
    const f16* __restrict__ wl = wf16l + gg * 12288;
    #pragma unroll
    for (int ct = 0; ct < 12; ct++){
        int g = ct * 16 + r16;
        f16x8 bh0 = *(const f16x8*)(wh + g * 64 + kg * 8);
        f16x8 bh1 = *(const f16x8*)(wh + g * 64 + 32 + kg * 8);
        f16x8 bl0 = *(const f16x8*)(wl + g * 64 + kg * 8);
        f16x8 bl1 = *(const f16x8*)(wl + g * 64 + 32 + kg * 8);
        f32x4 acc = {0.f, 0.f, 0.f, 0.f};
        acc = __builtin_amdgcn_mfma_f32_16x16x32_f16(ah[0], bh0, acc, 0, 0, 0);
        acc = __builtin_amdgcn_mfma_f32_16x16x32_f16(ah[1], bh1, acc, 0, 0, 0);
        acc = __builtin_amdgcn_mfma_f32_16x16x32_f16(ah[0], bl0, acc, 0, 0, 0);
        acc = __builtin_amdgcn_mfma_f32_16x16x32_f16(ah[1], bl1, acc, 0, 0, 0);
        acc = __builtin_amdgcn_mfma_f32_16x16x32_f16(al[0], bh0, acc, 0, 0, 0);
        acc = __builtin_amdgcn_mfma_f32_16x16x32_f16(al[1], bh1, acc, 0, 0, 0);
        #pragma unroll
        for (int r = 0; r < 4; r++)
            s_g[gg][rt * 16 + kg * 4 + r][ct * 16 + r16] = acc[r];
    }
    __syncthreads();

    int node = t >> 3;
    int f0 = (t & 7) * 8;
    int n2 = base + node;
    #pragma unroll
    for (int j = 0; j < 8; j++){
        int f = f0 + j;
        float gir = s_g[0][node][f]       + effb[f];
        float giz = s_g[0][node][64 + f]  + effb[64 + f];
        float gin = s_g[0][node][128 + f] + effb[128 + f];
        float ghr = s_g[1][node][f]       + bhh[f];
        float ghz = s_g[1][node][64 + f]  + bhh[64 + f];
        float ghn = s_g[1][node][128 + f] + bhh[128 + f];
        float r = sigmoidf_(gir + ghr);
        float z = sigmoidf_(giz + ghz);
        float nv = tanhf_(gin + r * ghn);
        size_t hb = (size_t)n2 * 64 + f;
        float hv = h[hb];
        h[hb] = (1.f - z) * nv + z * hv;
        m[hb] = 0.f;                         // re-zero for next step's atomics
    }
}

// ---------------- Set2Set + final projection: one block per graph ------------
__global__ __launch_bounds__(256) void set2set_kernel(
    const float* __restrict__ out, const int* __restrict__ offs,
    const float* __restrict__ lsT, const float* __restrict__ ls_bih,
    const float* __restrict__ ls_bhh, const float* __restrict__ lin3T,
    const float* __restrict__ lin3_b, const float* __restrict__ pred_w,
    const float* __restrict__ pred_b, float* __restrict__ e_ws,
    float* __restrict__ pred_out)
{
    int g = blockIdx.x;
    int t = threadIdx.x;
    int ln = t >> 6, d = t & 63;
    __shared__ float s_qstar[128], s_h[3][64], s_c[3][64], s_g[256];
    __shared__ float s_r[4][64], s_red[4], s_wsum[4], s_y[128];
    if (t < 128) s_qstar[t] = 0.f;
    if (t < 192){ s_h[t / 64][t % 64] = 0.f; s_c[t / 64][t % 64] = 0.f; }
    int ns = offs[g], ne = offs[g + 1];
    __syncthreads();

#define LSTM_GATE(L)                                                         \
    __syncthreads();                                                         \
    s_g[t] = acc;                                                            \
    __syncthreads();                                                         \
    if (t < 64){                                                             \
        float iv = s_g[t], fv = s_g[64 + t], gv = s_g[128 + t], ov = s_g[192 + t]; \
        float c2 = sigmoidf_(fv) * s_c[L][t] + sigmoidf_(iv) * tanhf_(gv);   \
        float h2 = sigmoidf_(ov) * tanhf_(c2);                               \
        s_c[L][t] = c2; s_h[L][t] = h2;                                      \
    }                                                                        \
    __syncthreads();

    for (int it = 0; it < 6; it++){
        {   // layer 0: x = q_star (128)
            float acc = ls_bih[t] + ls_bhh[t];
            const float* wx = lsT;                       // [128][256]
            #pragma unroll 32
            for (int j = 0; j < 128; j++) acc = fmaf(s_qstar[j], wx[j * 256 + t], acc);
            const float* wh = lsT + 65536;               // whh[0]: [64][256]
            #pragma unroll 32
            for (int j = 0; j < 64; j++) acc = fmaf(s_h[0][j], wh[j * 256 + t], acc);
            LSTM_GATE(0)
        }
        {   // layer 1: x = h0 (64)
            float acc = ls_bih[256 + t] + ls_bhh[256 + t];
            const float* wx = lsT + 32768;               // wih12[0]: [64][256]
            #pragma unroll 32
            for (int j = 0; j < 64; j++) acc = fmaf(s_h[0][j], wx[j * 256 + t], acc);
            const float* wh = lsT + 65536 + 16384;       // whh[1]
            #pragma unroll 32
            for (int j = 0; j < 64; j++) acc = fmaf(s_h[1][j], wh[j * 256 + t], acc);
            LSTM_GATE(1)
        }
        {   // layer 2: x = h1 (64)
            float acc = ls_bih[512 + t] + ls_bhh[512 + t];
            const float* wx = lsT + 32768 + 16384;       // wih12[1]
            #pragma unroll 32
            for (int j = 0; j < 64; j++) acc = fmaf(s_h[1][j], wx[j * 256 + t], acc);
            const float* wh = lsT + 65536 + 2 * 16384;   // whh[2]
            #pragma unroll 32
            for (int j = 0; j < 64; j++) acc = fmaf(s_h[2][j], wh[j * 256 + t], acc);
            LSTM_GATE(2)
        }
        // attention: q = s_h[2]
        float wmax = -3.4e38f;
        #pragma unroll 2
        for (int n = ns + ln; n < ne; n += 4){
            float p = out[(size_t)n * 64 + d] * s_h[2][d];
            #pragma unroll
            for (int o = 1; o < 64; o <<= 1) p += __shfl_xor(p, o);
            if (d == 0) e_ws[n] = p;
            wmax = fmaxf(wmax, p);
        }
        if (d == 0) s_red[ln] = wmax;
        __syncthreads();
        float gmax = fmaxf(fmaxf(s_red[0], s_red[1]), fmaxf(s_red[2], s_red[3]));
        float wsum = 0.f, racc = 0.f;
        #pragma unroll 2
        for (int n = ns + ln; n < ne; n += 4){
            float w = __expf(e_ws[n] - gmax);
            wsum += w;
            racc = fmaf(w, out[(size_t)n * 64 + d], racc);
        }
        s_r[ln][d] = racc;
        if (d == 0) s_wsum[ln] = wsum;
        __syncthreads();
        if (t < 64){
            float gsum = s_wsum[0] + s_wsum[1] + s_wsum[2] + s_wsum[3];
            float ro = s_r[0][t] + s_r[1][t] + s_r[2][t] + s_r[3][t];
            ro = (gsum > 0.f) ? ro / gsum : 0.f;
            s_qstar[t] = s_h[2][t];
            s_qstar[64 + t] = ro;
        }
        __syncthreads();
    }
#undef LSTM_GATE
    if (t < 128){
        float acc = lin3_b[t];
        #pragma unroll 32
        for (int i = 0; i < 128; i++) acc = fmaf(s_qstar[i], lin3T[i * 128 + t], acc);
        s_y[t] = fmaxf(acc, 0.f);
    }
    __syncthreads();
    if (t < 64){
        float p = s_y[t] * pred_w[t] + s_y[64 + t] * pred_w[64 + t];
        #pragma unroll
        for (int o = 1; o < 64; o <<= 1) p += __shfl_xor(p, o);
        if (t == 0) pred_out[g] = p + pred_b[0];
    }
}

extern "C" void kernel_launch(void* const* d_in, const int* in_sizes, int n_in,
                              void* d_out, int out_size, void* d_ws, size_t ws_size,
                              hipStream_t stream)
{
    (void)in_sizes; (void)n_in; (void)out_size; (void)ws_size;
    const float* n_feat  = (const float*)d_in[0];
    const float* e_feat  = (const float*)d_in[1];
    const int*   src     = (const int*)d_in[2];
    const int*   dst     = (const int*)d_in[3];
    const int*   node_graph = (const int*)d_in[4];
    const float* lin0_w  = (const float*)d_in[6];
    const float* lin0_b  = (const float*)d_in[7];
    const float* en_w1   = (const float*)d_in[8];
    const float* en_b1   = (const float*)d_in[9];
    const float* en_w2   = (const float*)d_in[10];
    const float* en_b2   = (const float*)d_in[11];
    const float* conv_b  = (const float*)d_in[12];
    const float* gru_wih = (const float*)d_in[13];
    const float* gru_whh = (const float*)d_in[14];
    const float* gru_bih = (const float*)d_in[15];
    const float* gru_bhh = (const float*)d_in[16];
    const float* ls_wih0 = (const float*)d_in[17];
    const float* ls_wih12= (const float*)d_in[18];
    const float* ls_whh  = (const float*)d_in[19];
    const float* ls_bih  = (const float*)d_in[20];
    const float* ls_bhh  = (const float*)d_in[21];
    const float* lin3_w  = (const float*)d_in[22];
    const float* lin3_b  = (const float*)d_in[23];
    const float* pred_w  = (const float*)d_in[24];
    const float* pred_b  = (const float*)d_in[25];

    float* h = (float*)d_out;                       // N x 64 (also "out")
    float* pred_out = (float*)d_out + (size_t)NN * 64;

    char* ws = (char*)d_ws;
    f16*   hidh  = (f16*)(ws + 0);                  // 25,600,000
    float* m     = (float*)(ws + 25600000);         // 10,240,000
    f16*   w2h   = (f16*)(ws + 35840000);           //  1,048,576
    f16*   wf16h = (f16*)(ws + 36888576);           //     49,152
    f16*   wf16l = (f16*)(ws + 36937728);           //     49,152
    float* lsT   = (float*)(ws + 36986880);         //    458,752
    float* lin3T = (float*)(ws + 37445632);         //     65,536
    float* effb  = (float*)(ws + 37511168);         //        768
    float* e_ws  = (float*)(ws + 37511936);         //    160,000
    int*   offs  = (int*)(ws + 37671936);           //      1,028

    prep_kernel<<<2754, 256, 0, stream>>>(en_w2, w2h, gru_wih, gru_whh,
                                          wf16h, wf16l,
                                          ls_wih0, ls_wih12, ls_whh, lsT,
                                          lin3_w, lin3T, gru_bih, conv_b, effb,
                                          node_graph, offs);
    lin0_kernel<<<(NN * 64) / 256, 256, 0, stream>>>(n_feat, lin0_w, lin0_b, h);
    edge_hidden_kernel<<<(EE * 128) / 256, 256, 0, stream>>>(e_feat, en_w1, en_b1, hidh);
    hipMemsetAsync(m, 0, (size_t)NN * 64 * sizeof(float), stream);

    for (int step = 0; step < 6; step++){
        msg_fused_kernel<<<(EE + EPB - 1) / EPB, 512, 0, stream>>>(h, hidh, w2h,
                                                                   en_b2, src, dst, m);
        gru_mfma_kernel<<<NN / 32, 256, 0, stream>>>(m, h, wf16h, wf16l, effb, gru_bhh);
    }

    set2set_kernel<<<BB, 256, 0, stream>>>(h, offs, lsT, ls_bih, ls_bhh,
                                           lin3T, lin3_b, pred_w, pred_b,
                                           e_ws, pred_out);
}

// Round 20
// 1269.478 us; speedup vs baseline: 1.0816x; 1.0816x over previous
//
#include <hip/hip_runtime.h>

typedef unsigned short u16;
typedef unsigned int u32;
typedef _Float16 f16;
typedef __attribute__((ext_vector_type(8))) _Float16 f16x8;
typedef __attribute__((ext_vector_type(4))) _Float16 f16x4;
typedef __attribute__((ext_vector_type(4))) float f32x4;

#define NN 40000
#define EE 100000
#define DD 64
#define BB 256
#define XTS 136  // s_xT stride (f16): 272B rows, 16B-aligned
#define EPB 128  // edges per block; 8 waves = 4 edge-groups x 2 col-pairs

__device__ inline float sigmoidf_(float x){
    return 1.f / (1.f + __expf(-x));
}
__device__ inline float tanhf_(float x){
    x = fmaxf(fminf(x, 15.f), -15.f);
    float e = __expf(2.f * x);
    return (e - 1.f) / (e + 1.f);
}

typedef __attribute__((address_space(3))) unsigned int lds_u32;
typedef __attribute__((address_space(1))) const unsigned int g_u32;
__device__ inline void gload_lds16(const void* g, void* l){
    __builtin_amdgcn_global_load_lds((g_u32*)g, (lds_u32*)l, 16, 0, 0);
}

// ---------------- prep: converts, transposes, eff bias, offsets --------------
__global__ __launch_bounds__(256) void prep_kernel(
    const float* __restrict__ en_w2, f16* __restrict__ w2h,
    const float* __restrict__ gru_wih, const float* __restrict__ gru_whh,
    f16* __restrict__ wf16h, f16* __restrict__ wf16l,
    const float* __restrict__ ls_wih0, const float* __restrict__ ls_wih12,
    const float* __restrict__ ls_whh, float* __restrict__ lsT,
    const float* __restrict__ lin3_w, float* __restrict__ lin3T,
    const float* __restrict__ gru_bih, const float* __restrict__ conv_b,
    float* __restrict__ effb,
    const int* __restrict__ node_graph, int* __restrict__ offs)
{
    int i = blockIdx.x * 256 + threadIdx.x;
    if (i < 524288){
        w2h[i] = (f16)en_w2[i];
        return;
    }
    i -= 524288;
    if (i < 49152){                       // GRU weights -> f16 hi/lo, [gg][g][d]
        int sel = i / 12288;              // 0:ih-hi 1:ih-lo 2:hh-hi 3:hh-lo
        int r = i % 12288;
        int gg = sel >> 1, islo = sel & 1;
        float v = (gg ? gru_whh : gru_wih)[r];
        f16 hi = (f16)v;
        if (islo) wf16l[gg * 12288 + r] = (f16)(v - (float)hi);
        else      wf16h[gg * 12288 + r] = hi;
        return;
    }
    i -= 49152;
    if (i < 114688){
        float v;
        if (i < 32768){
            int d = i >> 8, g = i & 255;
            v = ls_wih0[g * 128 + d];
        } else if (i < 65536){
            int j = i - 32768;
            int l = j >> 14, r = j & 16383;
            int d = r >> 8, g = r & 255;
            v = ls_wih12[l * 16384 + g * 64 + d];
        } else {
            int j = i - 65536;
            int l = j >> 14, r = j & 16383;
            int d = r >> 8, g = r & 255;
            v = ls_whh[l * 16384 + g * 64 + d];
        }
        lsT[i] = v;
        return;
    }
    i -= 114688;
    if (i < 16384){
        int ii = i >> 7, jj = i & 127;
        lin3T[i] = lin3_w[jj * 128 + ii];
        return;
    }
    i -= 16384;
    if (i < 192){
        float b = gru_bih[i];
        #pragma unroll
        for (int d = 0; d < 64; d++) b += gru_wih[i * 64 + d] * conv_b[d];
        effb[i] = b;
        return;
    }
    i -= 192;
    if (i <= 256){
        int lo = 0, hi = NN;
        while (lo < hi){
            int mid = (lo + hi) >> 1;
            if (node_graph[mid] < i) lo = mid + 1; else hi = mid;
        }
        offs[i] = lo;
        return;
    }
}

// ---------------- lin0: out = n_feat @ lin0_w^T + b  (writes h in d_out) -----
__global__ __launch_bounds__(256) void lin0_kernel(
    const float* __restrict__ nf, const float* __restrict__ w,
    const float* __restrict__ b, float* __restrict__ out)
{
    int tid = blockIdx.x * 256 + threadIdx.x;
    int n = tid >> 6, d = tid & 63;
    if (n >= NN) return;
    float acc = b[d];
    const float* nr = nf + (size_t)n * 23;
    const float* wr = w + d * 23;
    #pragma unroll
    for (int j = 0; j < 23; j++) acc = fmaf(nr[j], wr[j], acc);
    out[(size_t)n * 64 + d] = acc;
}

// ---------------- edge hidden: relu(e_feat @ w1^T + b1) -> f16 ---------------
__global__ __launch_bounds__(256) void edge_hidden_kernel(
    const float* __restrict__ ef, const float* __restrict__ w1,
    const float* __restrict__ b1, f16* __restrict__ hidh)
{
    int tid = blockIdx.x * 256 + threadIdx.x;
    int e = tid >> 7, k = tid & 127;
    if (e >= EE) return;
    float acc = b1[k];
    const float* er = ef + (size_t)e * 19;
    const float* wr = w1 + k * 19;
    #pragma unroll
    for (int j = 0; j < 19; j++) acc = fmaf(er[j], wr[j], acc);
    acc = fmaxf(acc, 0.f);
    hidh[(size_t)e * 128 + k] = (f16)acc;
}

// ---------------- fused msg: 3-buffer counted-vmcnt pipeline (R15 scheme,
// now at 2 blocks/CU thanks to f16 s_xT) -------------------------------------
// msg[e,f] = sum_d x[e,d] * ( sum_k u[e,k]*W2[d*64+f,k] + b2[d*64+f] )
// Tile d+2 issued at top of iter d; end-of-iter s_waitcnt vmcnt(2) (tile d+1
// complete, d+2 in flight) + raw s_barrier -- each tile gets a full
// iteration+ of DMA latency cover vs R18's same-iteration drain. b2 staged
// to LDS f16 so in-loop VMEM = exactly the 2 DMA issues (vmcnt count exact).
__global__ __launch_bounds__(512) void msg_fused_kernel(
    const float* __restrict__ h, const f16* __restrict__ hidh,
    const f16* __restrict__ w2h, const float* __restrict__ b2,
    const int* __restrict__ src, const int* __restrict__ dst,
    float* __restrict__ m)
{
    __shared__ f16 s_xT[64 * XTS];           // [d][el] transposed x, f16 (17.4 KB)
    __shared__ f16 s_b2f[4096];              // bias tile, f16 (8 KB)
    __shared__ int s_dst[EPB];
    __shared__ f16x8 s_t0[1024], s_t1[1024], s_t2[1024];  // 3 x 16 KB B tiles

    const int t = threadIdx.x;
    const int base = blockIdx.x * EPB;
    const int lane = t & 63;
    const int wid = t >> 6;

    int goff[2], lbase[2];
    #pragma unroll
    for (int cc = 0; cc < 2; cc++){
        int s = cc * 512 + wid * 64 + lane;
        int kh = s >> 9;
        int c2 = s & 511;
        int col = c2 >> 3;
        int jj = (c2 & 7) ^ (col & 7);
        goff[cc] = col * 128 + kh * 64 + jj * 8;
        lbase[cc] = cc * 512 + wid * 64;
    }

#define STG_ISSUE(DN, BUF)                                                   \
    {                                                                        \
        const f16* gsrc = w2h + (size_t)(DN) * 8192;                         \
        gload_lds16(gsrc + goff[0], (BUF) + lbase[0]);                       \
        gload_lds16(gsrc + goff[1], (BUF) + lbase[1]);                       \
    }

    f16x8* pb0 = s_t0;                       // tile d (ready at loop top)
    f16x8* pb1 = s_t1;                       // tile d+1
    f16x8* pb2 = s_t2;                       // DMA target for tile d+2
    STG_ISSUE(0, pb0);
    STG_ISSUE(1, pb1);

    for (int i = t; i < EPB * 64; i += 512){
        int el = i >> 6, f = i & 63;
        int e = base + el;
        float v = 0.f;
        if (e < EE) v = h[(size_t)src[e] * 64 + f];
        s_xT[f * XTS + el] = (f16)v;
    }
    for (int i = t; i < 4096; i += 512) s_b2f[i] = (f16)b2[i];
    if (t < EPB){
        int e = base + t;
        s_dst[t] = (e < EE) ? dst[e] : -1;
    }

    const int eg = wid >> 1;                 // edge group: 32 edges
    const int fp = wid & 1;                  // col pair: cols fp*32..fp*32+31
    const int r16 = lane & 15;
    const int kg = lane >> 4;
    const int we = eg * 32;
    const int sw = r16 & 7;

    // A fragments, full K: 8 frags = 32 VGPR
    f16x8 ah[2][4];
    #pragma unroll
    for (int mt = 0; mt < 2; mt++){
        int e = base + we + mt * 16 + r16;
        #pragma unroll
        for (int ks = 0; ks < 4; ks++){
            if (e < EE){
                ah[mt][ks] = *(const f16x8*)(hidh + (size_t)e * 128 + ks * 32 + kg * 8);
            } else {
                f16x8 z = {0,0,0,0,0,0,0,0};
                ah[mt][ks] = z;
            }
        }
    }

    f32x4 msg[2][2];                         // [mt][ftl]: 16 VGPR
    #pragma unroll
    for (int a = 0; a < 2; a++)
        #pragma unroll
        for (int b = 0; b < 2; b++){
            f32x4 z = {0.f, 0.f, 0.f, 0.f};
            msg[a][b] = z;
        }

    int rslot[2][4];
    #pragma unroll
    for (int ftl = 0; ftl < 2; ftl++){
        int col = fp * 32 + ftl * 16 + r16;
        #pragma unroll
        for (int ks = 0; ks < 4; ks++){
            int j2 = (ks & 1) * 4 + kg;
            rslot[ftl][ks] = (ks >> 1) * 512 + col * 8 + (j2 ^ sw);
        }
    }

    __syncthreads();                         // tiles 0,1 + s_xT/s_b2f/s_dst ready

    for (int d = 0; d < 64; d++){
        if (d + 2 < 64) STG_ISSUE(d + 2, pb2);   // async DMA, stays in flight
        f32x4 xv[2];
        #pragma unroll
        for (int mt = 0; mt < 2; mt++){
            f16x4 xh = *(const f16x4*)&s_xT[d * XTS + we + mt * 16 + kg * 4];
            #pragma unroll
            for (int r = 0; r < 4; r++) xv[mt][r] = (float)xh[r];
        }
        __builtin_amdgcn_s_setprio(1);
        #pragma unroll
        for (int ftl = 0; ftl < 2; ftl++){
            f16x8 bf0 = pb0[rslot[ftl][0]];
            f16x8 bf1 = pb0[rslot[ftl][1]];
            f16x8 bf2 = pb0[rslot[ftl][2]];
            f16x8 bf3 = pb0[rslot[ftl][3]];
            float b2v = (float)s_b2f[d * 64 + fp * 32 + ftl * 16 + r16];
            #pragma unroll
            for (int mt = 0; mt < 2; mt++){
                f32x4 acc = {b2v, b2v, b2v, b2v};
                acc = __builtin_amdgcn_mfma_f32_16x16x32_f16(ah[mt][0], bf0, acc, 0, 0, 0);
                acc = __builtin_amdgcn_mfma_f32_16x16x32_f16(ah[mt][1], bf1, acc, 0, 0, 0);
                acc = __builtin_amdgcn_mfma_f32_16x16x32_f16(ah[mt][2], bf2, acc, 0, 0, 0);
                acc = __builtin_amdgcn_mfma_f32_16x16x32_f16(ah[mt][3], bf3, acc, 0, 0, 0);
                msg[mt][ftl] = xv[mt] * acc + msg[mt][ftl];
            }
        }
        __builtin_amdgcn_s_setprio(0);
        if (d < 63){
            if (d <= 61) asm volatile("s_waitcnt vmcnt(2)" ::: "memory");
            else         asm volatile("s_waitcnt vmcnt(0)" ::: "memory");
            __builtin_amdgcn_s_barrier();
        }
        f16x8* tmp = pb0; pb0 = pb1; pb1 = pb2; pb2 = tmp;
    }
#undef STG_ISSUE

    // scatter-add: wave owns (eg edges) x (fp cols) -> each output added once
    #pragma unroll
    for (int mt = 0; mt < 2; mt++){
        #pragma unroll
        for (int r = 0; r < 4; r++){
            int el = we + mt * 16 + kg * 4 + r;
            int dt = s_dst[el];
            if (dt >= 0){
                #pragma unroll
                for (int ftl = 0; ftl < 2; ftl++)
                    atomicAdd(&m[(size_t)dt * 64 + fp * 32 + ftl * 16 + r16],
                              msg[mt][ftl][r]);
            }
        }
    }
}

// ---------------- GRU via MFMA: G = X @ W^T (3-mfma hi/lo), gate, h in-place -
__global__ __launch_bounds__(256) void gru_mfma_kernel(
    float* __restrict__ m, float* __restrict__ h,
    const f16* __restrict__ wf16h, const f16* __restrict__ wf16l,
    const float* __restrict__ effb, const float* __restrict__ bhh)
{
    __shared__ float s_g[2][32][194];
    const int t = threadIdx.x;
    const int base = blockIdx.x * 32;
    const int lane = t & 63;
    const int wid = t >> 6;
    const int rt = wid & 1;
    const int gg = wid >> 1;
    const int r16 = lane & 15;
    const int kg = lane >> 4;

    const float* __restrict__ X = gg ? h : m;
    int n = base + rt * 16 + r16;            // 40000 % 32 == 0 -> always valid

    f16x8 ah[2], al[2];
    #pragma unroll
    for (int ks = 0; ks < 2; ks++){
        const float* xp = X + (size_t)n * 64 + ks * 32 + kg * 8;
        f32x4 v0 = *(const f32x4*)(xp);
        f32x4 v1 = *(const f32x4*)(xp + 4);
        #pragma unroll
        for (int j = 0; j < 4; j++){
            f16 hi0 = (f16)v0[j], hi1 = (f16)v1[j];
            ah[ks][j] = hi0;     ah[ks][4 + j] = hi1;
            al[ks][j] = (f16)(v0[j] - (float)hi0);
            al[ks][4 + j] = (f16)(v1[j] - (float)hi1);
        }
    }

    const f16* __restrict__ wh = wf16h + gg * 12288;
    const f16* __restrict__ wl = wf16l + gg * 12288;
    #pragma unroll
    for (int ct = 0; ct < 12; ct++){
        int g = ct * 16 + r16;
        f16x8 bh0 = *(const f16x8*)(wh + g * 64 + kg * 8);
        f16x8 bh1 = *(const f16x8*)(wh + g * 64 + 32 + kg * 8);
        f16x8 bl0 = *(const f16x8*)(wl + g * 64 + kg * 8);
        f16x8 bl1 = *(const f16x8*)(wl + g * 64 + 32 + kg * 8);
        f32x4 acc = {0.f, 0.f, 0.f, 0.f};
        acc = __builtin_amdgcn_mfma_f32_16x16x32_f16(ah[0], bh0, acc, 0, 0, 0);
        acc = __builtin_amdgcn_mfma_f32_16x16x32_f16(ah[1], bh1, acc, 0, 0, 0);
        acc = __builtin_amdgcn_mfma_f32_16x16x32_f16(ah[0], bl0, acc, 0, 0, 0);
        acc = __builtin_amdgcn_mfma_f32_16x16x32_f16(ah[1], bl1, acc, 0, 0, 0);
        acc = __builtin_amdgcn_mfma_f32_16x16x32_f16(al[0], bh0, acc, 0, 0, 0);
        acc = __builtin_amdgcn_mfma_f32_16x16x32_f16(al[1], bh1, acc, 0, 0, 0);
        #pragma unroll
        for (int r = 0; r < 4; r++)
            s_g[gg][rt * 16 + kg * 4 + r][ct * 16 + r16] = acc[r];
    }
    __syncthreads();

    int node = t >> 3;
    int f0 = (t & 7) * 8;
    int n2 = base + node;
    #pragma unroll
    for (int j = 0; j < 8; j++){
        int f = f0 + j;
        float gir = s_g[0][node][f]       + effb[f];
        float giz = s_g[0][node][64 + f]  + effb[64 + f];
        float gin = s_g[0][node][128 + f] + effb[128 + f];
        float ghr = s_g[1][node][f]       + bhh[f];
        float ghz = s_g[1][node][64 + f]  + bhh[64 + f];
        float ghn = s_g[1][node][128 + f] + bhh[128 + f];
        float r = sigmoidf_(gir + ghr);
        float z = sigmoidf_(giz + ghz);
        float nv = tanhf_(gin + r * ghn);
        size_t hb = (size_t)n2 * 64 + f;
        float hv = h[hb];
        h[hb] = (1.f - z) * nv + z * hv;
        m[hb] = 0.f;                         // re-zero for next step's atomics
    }
}

// ---------------- Set2Set + final projection: one block per graph ------------
__global__ __launch_bounds__(256) void set2set_kernel(
    const float* __restrict__ out, const int* __restrict__ offs,
    const float* __restrict__ lsT, const float* __restrict__ ls_bih,
    const float* __restrict__ ls_bhh, const float* __restrict__ lin3T,
    const float* __restrict__ lin3_b, const float* __restrict__ pred_w,
    const float* __restrict__ pred_b, float* __restrict__ e_ws,
    float* __restrict__ pred_out)
{
    int g = blockIdx.x;
    int t = threadIdx.x;
    int ln = t >> 6, d = t & 63;
    __shared__ float s_qstar[128], s_h[3][64], s_c[3][64], s_g[256];
    __shared__ float s_r[4][64], s_red[4], s_wsum[4], s_y[128];
    if (t < 128) s_qstar[t] = 0.f;
    if (t < 192){ s_h[t / 64][t % 64] = 0.f; s_c[t / 64][t % 64] = 0.f; }
    int ns = offs[g], ne = offs[g + 1];
    __syncthreads();

#define LSTM_GATE(L)                                                         \
    __syncthreads();                                                         \
    s_g[t] = acc;                                                            \
    __syncthreads();                                                         \
    if (t < 64){                                                             \
        float iv = s_g[t], fv = s_g[64 + t], gv = s_g[128 + t], ov = s_g[192 + t]; \
        float c2 = sigmoidf_(fv) * s_c[L][t] + sigmoidf_(iv) * tanhf_(gv);   \
        float h2 = sigmoidf_(ov) * tanhf_(c2);                               \
        s_c[L][t] = c2; s_h[L][t] = h2;                                      \
    }                                                                        \
    __syncthreads();

    for (int it = 0; it < 6; it++){
        {   // layer 0: x = q_star (128)
            float acc = ls_bih[t] + ls_bhh[t];
            const float* wx = lsT;                       // [128][256]
            #pragma unroll 32
            for (int j = 0; j < 128; j++) acc = fmaf(s_qstar[j], wx[j * 256 + t], acc);
            const float* wh = lsT + 65536;               // whh[0]: [64][256]
            #pragma unroll 32
            for (int j = 0; j < 64; j++) acc = fmaf(s_h[0][j], wh[j * 256 + t], acc);
            LSTM_GATE(0)
        }
        {   // layer 1: x = h0 (64)
            float acc = ls_bih[256 + t] + ls_bhh[256 + t];
            const float* wx = lsT + 32768;               // wih12[0]: [64][256]
            #pragma unroll 32
            for (int j = 0; j < 64; j++) acc = fmaf(s_h[0][j], wx[j * 256 + t], acc);
            const float* wh = lsT + 65536 + 16384;       // whh[1]
            #pragma unroll 32
            for (int j = 0; j < 64; j++) acc = fmaf(s_h[1][j], wh[j * 256 + t], acc);
            LSTM_GATE(1)
        }
        {   // layer 2: x = h1 (64)
            float acc = ls_bih[512 + t] + ls_bhh[512 + t];
            const float* wx = lsT + 32768 + 16384;       // wih12[1]
            #pragma unroll 32
            for (int j = 0; j < 64; j++) acc = fmaf(s_h[1][j], wx[j * 256 + t], acc);
            const float* wh = lsT + 65536 + 2 * 16384;   // whh[2]
            #pragma unroll 32
            for (int j = 0; j < 64; j++) acc = fmaf(s_h[2][j], wh[j * 256 + t], acc);
            LSTM_GATE(2)
        }
        // attention: q = s_h[2]
        float wmax = -3.4e38f;
        #pragma unroll 2
        for (int n = ns + ln; n < ne; n += 4){
            float p = out[(size_t)n * 64 + d] * s_h[2][d];
            #pragma unroll
            for (int o = 1; o < 64; o <<= 1) p += __shfl_xor(p, o);
            if (d == 0) e_ws[n] = p;
            wmax = fmaxf(wmax, p);
        }
        if (d == 0) s_red[ln] = wmax;
        __syncthreads();
        float gmax = fmaxf(fmaxf(s_red[0], s_red[1]), fmaxf(s_red[2], s_red[3]));
        float wsum = 0.f, racc = 0.f;
        #pragma unroll 2
        for (int n = ns + ln; n < ne; n += 4){
            float w = __expf(e_ws[n] - gmax);
            wsum += w;
            racc = fmaf(w, out[(size_t)n * 64 + d], racc);
        }
        s_r[ln][d] = racc;
        if (d == 0) s_wsum[ln] = wsum;
        __syncthreads();
        if (t < 64){
            float gsum = s_wsum[0] + s_wsum[1] + s_wsum[2] + s_wsum[3];
            float ro = s_r[0][t] + s_r[1][t] + s_r[2][t] + s_r[3][t];
            ro = (gsum > 0.f) ? ro / gsum : 0.f;
            s_qstar[t] = s_h[2][t];
            s_qstar[64 + t] = ro;
        }
        __syncthreads();
    }
#undef LSTM_GATE
    if (t < 128){
        float acc = lin3_b[t];
        #pragma unroll 32
        for (int i = 0; i < 128; i++) acc = fmaf(s_qstar[i], lin3T[i * 128 + t], acc);
        s_y[t] = fmaxf(acc, 0.f);
    }
    __syncthreads();
    if (t < 64){
        float p = s_y[t] * pred_w[t] + s_y[64 + t] * pred_w[64 + t];
        #pragma unroll
        for (int o = 1; o < 64; o <<= 1) p += __shfl_xor(p, o);
        if (t == 0) pred_out[g] = p + pred_b[0];
    }
}

extern "C" void kernel_launch(void* const* d_in, const int* in_sizes, int n_in,
                              void* d_out, int out_size, void* d_ws, size_t ws_size,
                              hipStream_t stream)
{
    (void)in_sizes; (void)n_in; (void)out_size; (void)ws_size;
    const float* n_feat  = (const float*)d_in[0];
    const float* e_feat  = (const float*)d_in[1];
    const int*   src     = (const int*)d_in[2];
    const int*   dst     = (const int*)d_in[3];
    const int*   node_graph = (const int*)d_in[4];
    const float* lin0_w  = (const float*)d_in[6];
    const float* lin0_b  = (const float*)d_in[7];
    const float* en_w1   = (const float*)d_in[8];
    const float* en_b1   = (const float*)d_in[9];
    const float* en_w2   = (const float*)d_in[10];
    const float* en_b2   = (const float*)d_in[11];
    const float* conv_b  = (const float*)d_in[12];
    const float* gru_wih = (const float*)d_in[13];
    const float* gru_whh = (const float*)d_in[14];
    const float* gru_bih = (const float*)d_in[15];
    const float* gru_bhh = (const float*)d_in[16];
    const float* ls_wih0 = (const float*)d_in[17];
    const float* ls_wih12= (const float*)d_in[18];
    const float* ls_whh  = (const float*)d_in[19];
    const float* ls_bih  = (const float*)d_in[20];
    const float* ls_bhh  = (const float*)d_in[21];
    const float* lin3_w  = (const float*)d_in[22];
    const float* lin3_b  = (const float*)d_in[23];
    const float* pred_w  = (const float*)d_in[24];
    const float* pred_b  = (const float*)d_in[25];

    float* h = (float*)d_out;                       // N x 64 (also "out")
    float* pred_out = (float*)d_out + (size_t)NN * 64;

    char* ws = (char*)d_ws;
    f16*   hidh  = (f16*)(ws + 0);                  // 25,600,000
    float* m     = (float*)(ws + 25600000);         // 10,240,000
    f16*   w2h   = (f16*)(ws + 35840000);           //  1,048,576
    f16*   wf16h = (f16*)(ws + 36888576);           //     49,152
    f16*   wf16l = (f16*)(ws + 36937728);           //     49,152
    float* lsT   = (float*)(ws + 36986880);         //    458,752
    float* lin3T = (float*)(ws + 37445632);         //     65,536
    float* effb  = (float*)(ws + 37511168);         //        768
    float* e_ws  = (float*)(ws + 37511936);         //    160,000
    int*   offs  = (int*)(ws + 37671936);           //      1,028

    prep_kernel<<<2754, 256, 0, stream>>>(en_w2, w2h, gru_wih, gru_whh,
                                          wf16h, wf16l,
                                          ls_wih0, ls_wih12, ls_whh, lsT,
                                          lin3_w, lin3T, gru_bih, conv_b, effb,
                                          node_graph, offs);
    lin0_kernel<<<(NN * 64) / 256, 256, 0, stream>>>(n_feat, lin0_w, lin0_b, h);
    edge_hidden_kernel<<<(EE * 128) / 256, 256, 0, stream>>>(e_feat, en_w1, en_b1, hidh);
    hipMemsetAsync(m, 0, (size_t)NN * 64 * sizeof(float), stream);

    for (int step = 0; step < 6; step++){
        msg_fused_kernel<<<(EE + EPB - 1) / EPB, 512, 0, stream>>>(h, hidh, w2h,
                                                                   en_b2, src, dst, m);
        gru_mfma_kernel<<<NN / 32, 256, 0, stream>>>(m, h, wf16h, wf16l, effb, gru_bhh);
    }

    set2set_kernel<<<BB, 256, 0, stream>>>(h, offs, lsT, ls_bih, ls_bhh,
                                           lin3T, lin3_b, pred_w, pred_b,
                                           e_ws, pred_out);
}

// Round 21
// 1179.400 us; speedup vs baseline: 1.1643x; 1.0764x over previous
//
#include <hip/hip_runtime.h>

typedef unsigned short u16;
typedef unsigned int u32;
typedef _Float16 f16;
typedef __attribute__((ext_vector_type(8))) _Float16 f16x8;
typedef __attribute__((ext_vector_type(4))) _Float16 f16x4;
typedef __attribute__((ext_vector_type(4))) float f32x4;

#define NN 40000
#define EE 100000
#define DD 64
#define BB 256
#define XTS 136  // s_xT stride (f16): 272B rows, 16B-aligned
#define EPB 128  // edges per block; 8 waves = 4 edge-groups x 2 col-pairs

__device__ inline float sigmoidf_(float x){
    return 1.f / (1.f + __expf(-x));
}
__device__ inline float tanhf_(float x){
    x = fmaxf(fminf(x, 15.f), -15.f);
    float e = __expf(2.f * x);
    return (e - 1.f) / (e + 1.f);
}

typedef __attribute__((address_space(3))) unsigned int lds_u32;
typedef __attribute__((address_space(1))) const unsigned int g_u32;
__device__ inline void gload_lds16(const void* g, void* l){
    __builtin_amdgcn_global_load_lds((g_u32*)g, (lds_u32*)l, 16, 0, 0);
}

// ---------------- prep: converts, transposes, eff bias, offsets --------------
__global__ __launch_bounds__(256) void prep_kernel(
    const float* __restrict__ en_w2, f16* __restrict__ w2h,
    const float* __restrict__ gru_wih, const float* __restrict__ gru_whh,
    f16* __restrict__ wf16h, f16* __restrict__ wf16l,
    const float* __restrict__ ls_wih0, const float* __restrict__ ls_wih12,
    const float* __restrict__ ls_whh, float* __restrict__ lsT,
    const float* __restrict__ lin3_w, float* __restrict__ lin3T,
    const float* __restrict__ gru_bih, const float* __restrict__ conv_b,
    float* __restrict__ effb,
    const int* __restrict__ node_graph, int* __restrict__ offs)
{
    int i = blockIdx.x * 256 + threadIdx.x;
    if (i < 524288){
        w2h[i] = (f16)en_w2[i];
        return;
    }
    i -= 524288;
    if (i < 49152){                       // GRU weights -> f16 hi/lo, [gg][g][d]
        int sel = i / 12288;              // 0:ih-hi 1:ih-lo 2:hh-hi 3:hh-lo
        int r = i % 12288;
        int gg = sel >> 1, islo = sel & 1;
        float v = (gg ? gru_whh : gru_wih)[r];
        f16 hi = (f16)v;
        if (islo) wf16l[gg * 12288 + r] = (f16)(v - (float)hi);
        else      wf16h[gg * 12288 + r] = hi;
        return;
    }
    i -= 49152;
    if (i < 114688){
        float v;
        if (i < 32768){
            int d = i >> 8, g = i & 255;
            v = ls_wih0[g * 128 + d];
        } else if (i < 65536){
            int j = i - 32768;
            int l = j >> 14, r = j & 16383;
            int d = r >> 8, g = r & 255;
            v = ls_wih12[l * 16384 + g * 64 + d];
        } else {
            int j = i - 65536;
            int l = j >> 14, r = j & 16383;
            int d = r >> 8, g = r & 255;
            v = ls_whh[l * 16384 + g * 64 + d];
        }
        lsT[i] = v;
        return;
    }
    i -= 114688;
    if (i < 16384){
        int ii = i >> 7, jj = i & 127;
        lin3T[i] = lin3_w[jj * 128 + ii];
        return;
    }
    i -= 16384;
    if (i < 192){
        float b = gru_bih[i];
        #pragma unroll
        for (int d = 0; d < 64; d++) b += gru_wih[i * 64 + d] * conv_b[d];
        effb[i] = b;
        return;
    }
    i -= 192;
    if (i <= 256){
        int lo = 0, hi = NN;
        while (lo < hi){
            int mid = (lo + hi) >> 1;
            if (node_graph[mid] < i) lo = mid + 1; else hi = mid;
        }
        offs[i] = lo;
        return;
    }
}

// ---------------- lin0: out = n_feat @ lin0_w^T + b  (writes h in d_out) -----
__global__ __launch_bounds__(256) void lin0_kernel(
    const float* __restrict__ nf, const float* __restrict__ w,
    const float* __restrict__ b, float* __restrict__ out)
{
    int tid = blockIdx.x * 256 + threadIdx.x;
    int n = tid >> 6, d = tid & 63;
    if (n >= NN) return;
    float acc = b[d];
    const float* nr = nf + (size_t)n * 23;
    const float* wr = w + d * 23;
    #pragma unroll
    for (int j = 0; j < 23; j++) acc = fmaf(nr[j], wr[j], acc);
    out[(size_t)n * 64 + d] = acc;
}

// ---------------- edge hidden: relu(e_feat @ w1^T + b1) -> f16 ---------------
__global__ __launch_bounds__(256) void edge_hidden_kernel(
    const float* __restrict__ ef, const float* __restrict__ w1,
    const float* __restrict__ b1, f16* __restrict__ hidh)
{
    int tid = blockIdx.x * 256 + threadIdx.x;
    int e = tid >> 7, k = tid & 127;
    if (e >= EE) return;
    float acc = b1[k];
    const float* er = ef + (size_t)e * 19;
    const float* wr = w1 + k * 19;
    #pragma unroll
    for (int j = 0; j < 19; j++) acc = fmaf(er[j], wr[j], acc);
    acc = fmaxf(acc, 0.f);
    hidh[(size_t)e * 128 + k] = (f16)acc;
}

// ---------------- fused msg: 3-buffer counted-vmcnt pipeline (proven R20) ----
__global__ __launch_bounds__(512) void msg_fused_kernel(
    const float* __restrict__ h, const f16* __restrict__ hidh,
    const f16* __restrict__ w2h, const float* __restrict__ b2,
    const int* __restrict__ src, const int* __restrict__ dst,
    float* __restrict__ m)
{
    __shared__ f16 s_xT[64 * XTS];           // [d][el] transposed x, f16 (17.4 KB)
    __shared__ f16 s_b2f[4096];              // bias tile, f16 (8 KB)
    __shared__ int s_dst[EPB];
    __shared__ f16x8 s_t0[1024], s_t1[1024], s_t2[1024];  // 3 x 16 KB B tiles

    const int t = threadIdx.x;
    const int base = blockIdx.x * EPB;
    const int lane = t & 63;
    const int wid = t >> 6;

    int goff[2], lbase[2];
    #pragma unroll
    for (int cc = 0; cc < 2; cc++){
        int s = cc * 512 + wid * 64 + lane;
        int kh = s >> 9;
        int c2 = s & 511;
        int col = c2 >> 3;
        int jj = (c2 & 7) ^ (col & 7);
        goff[cc] = col * 128 + kh * 64 + jj * 8;
        lbase[cc] = cc * 512 + wid * 64;
    }

#define STG_ISSUE(DN, BUF)                                                   \
    {                                                                        \
        const f16* gsrc = w2h + (size_t)(DN) * 8192;                         \
        gload_lds16(gsrc + goff[0], (BUF) + lbase[0]);                       \
        gload_lds16(gsrc + goff[1], (BUF) + lbase[1]);                       \
    }

    f16x8* pb0 = s_t0;                       // tile d (ready at loop top)
    f16x8* pb1 = s_t1;                       // tile d+1
    f16x8* pb2 = s_t2;                       // DMA target for tile d+2
    STG_ISSUE(0, pb0);
    STG_ISSUE(1, pb1);

    for (int i = t; i < EPB * 64; i += 512){
        int el = i >> 6, f = i & 63;
        int e = base + el;
        float v = 0.f;
        if (e < EE) v = h[(size_t)src[e] * 64 + f];
        s_xT[f * XTS + el] = (f16)v;
    }
    for (int i = t; i < 4096; i += 512) s_b2f[i] = (f16)b2[i];
    if (t < EPB){
        int e = base + t;
        s_dst[t] = (e < EE) ? dst[e] : -1;
    }

    const int eg = wid >> 1;                 // edge group: 32 edges
    const int fp = wid & 1;                  // col pair: cols fp*32..fp*32+31
    const int r16 = lane & 15;
    const int kg = lane >> 4;
    const int we = eg * 32;
    const int sw = r16 & 7;

    // A fragments, full K: 8 frags = 32 VGPR
    f16x8 ah[2][4];
    #pragma unroll
    for (int mt = 0; mt < 2; mt++){
        int e = base + we + mt * 16 + r16;
        #pragma unroll
        for (int ks = 0; ks < 4; ks++){
            if (e < EE){
                ah[mt][ks] = *(const f16x8*)(hidh + (size_t)e * 128 + ks * 32 + kg * 8);
            } else {
                f16x8 z = {0,0,0,0,0,0,0,0};
                ah[mt][ks] = z;
            }
        }
    }

    f32x4 msg[2][2];                         // [mt][ftl]: 16 VGPR
    #pragma unroll
    for (int a = 0; a < 2; a++)
        #pragma unroll
        for (int b = 0; b < 2; b++){
            f32x4 z = {0.f, 0.f, 0.f, 0.f};
            msg[a][b] = z;
        }

    int rslot[2][4];
    #pragma unroll
    for (int ftl = 0; ftl < 2; ftl++){
        int col = fp * 32 + ftl * 16 + r16;
        #pragma unroll
        for (int ks = 0; ks < 4; ks++){
            int j2 = (ks & 1) * 4 + kg;
            rslot[ftl][ks] = (ks >> 1) * 512 + col * 8 + (j2 ^ sw);
        }
    }

    __syncthreads();                         // tiles 0,1 + s_xT/s_b2f/s_dst ready

    for (int d = 0; d < 64; d++){
        if (d + 2 < 64) STG_ISSUE(d + 2, pb2);   // async DMA, stays in flight
        f32x4 xv[2];
        #pragma unroll
        for (int mt = 0; mt < 2; mt++){
            f16x4 xh = *(const f16x4*)&s_xT[d * XTS + we + mt * 16 + kg * 4];
            #pragma unroll
            for (int r = 0; r < 4; r++) xv[mt][r] = (float)xh[r];
        }
        __builtin_amdgcn_s_setprio(1);
        #pragma unroll
        for (int ftl = 0; ftl < 2; ftl++){
            f16x8 bf0 = pb0[rslot[ftl][0]];
            f16x8 bf1 = pb0[rslot[ftl][1]];
            f16x8 bf2 = pb0[rslot[ftl][2]];
            f16x8 bf3 = pb0[rslot[ftl][3]];
            float b2v = (float)s_b2f[d * 64 + fp * 32 + ftl * 16 + r16];
            #pragma unroll
            for (int mt = 0; mt < 2; mt++){
                f32x4 acc = {b2v, b2v, b2v, b2v};
                acc = __builtin_amdgcn_mfma_f32_16x16x32_f16(ah[mt][0], bf0, acc, 0, 0, 0);
                acc = __builtin_amdgcn_mfma_f32_16x16x32_f16(ah[mt][1], bf1, acc, 0, 0, 0);
                acc = __builtin_amdgcn_mfma_f32_16x16x32_f16(ah[mt][2], bf2, acc, 0, 0, 0);
                acc = __builtin_amdgcn_mfma_f32_16x16x32_f16(ah[mt][3], bf3, acc, 0, 0, 0);
                msg[mt][ftl] = xv[mt] * acc + msg[mt][ftl];
            }
        }
        __builtin_amdgcn_s_setprio(0);
        if (d < 63){
            if (d <= 61) asm volatile("s_waitcnt vmcnt(2)" ::: "memory");
            else         asm volatile("s_waitcnt vmcnt(0)" ::: "memory");
            __builtin_amdgcn_s_barrier();
        }
        f16x8* tmp = pb0; pb0 = pb1; pb1 = pb2; pb2 = tmp;
    }
#undef STG_ISSUE

    // scatter-add: wave owns (eg edges) x (fp cols) -> each output added once
    #pragma unroll
    for (int mt = 0; mt < 2; mt++){
        #pragma unroll
        for (int r = 0; r < 4; r++){
            int el = we + mt * 16 + kg * 4 + r;
            int dt = s_dst[el];
            if (dt >= 0){
                #pragma unroll
                for (int ftl = 0; ftl < 2; ftl++)
                    atomicAdd(&m[(size_t)dt * 64 + fp * 32 + ftl * 16 + r16],
                              msg[mt][ftl][r]);
            }
        }
    }
}

// ---------------- GRU via MFMA: G = X @ W^T (3-mfma hi/lo), gate, h in-place -
__global__ __launch_bounds__(256) void gru_mfma_kernel(
    float* __restrict__ m, float* __restrict__ h,
    const f16* __restrict__ wf16h, const f16* __restrict__ wf16l,
    const float* __restrict__ effb, const float* __restrict__ bhh)
{
    __shared__ float s_g[2][32][194];
    const int t = threadIdx.x;
    const int base = blockIdx.x * 32;
    const int lane = t & 63;
    const int wid = t >> 6;
    const int rt = wid & 1;
    const int gg = wid >> 1;
    const int r16 = lane & 15;
    const int kg = lane >> 4;

    const float* __restrict__ X = gg ? h : m;
    int n = base + rt * 16 + r16;            // 40000 % 32 == 0 -> always valid

    f16x8 ah[2], al[2];
    #pragma unroll
    for (int ks = 0; ks < 2; ks++){
        const float* xp = X + (size_t)n * 64 + ks * 32 + kg * 8;
        f32x4 v0 = *(const f32x4*)(xp);
        f32x4 v1 = *(const f32x4*)(xp + 4);
        #pragma unroll
        for (int j = 0; j < 4; j++){
            f16 hi0 = (f16)v0[j], hi1 = (f16)v1[j];
            ah[ks][j] = hi0;     ah[ks][4 + j] = hi1;
            al[ks][j] = (f16)(v0[j] - (float)hi0);
            al[ks][4 + j] = (f16)(v1[j] - (float)hi1);
        }
    }

    const f16* __restrict__ wh = wf16h + gg * 12288;
    const f16* __restrict__ wl = wf16l + gg * 12288;
    #pragma unroll
    for (int ct = 0; ct < 12; ct++){
        int g = ct * 16 + r16;
        f16x8 bh0 = *(const f16x8*)(wh + g * 64 + kg * 8);
        f16x8 bh1 = *(const f16x8*)(wh + g * 64 + 32 + kg * 8);
        f16x8 bl0 = *(const f16x8*)(wl + g * 64 + kg * 8);
        f16x8 bl1 = *(const f16x8*)(wl + g * 64 + 32 + kg * 8);
        f32x4 acc = {0.f, 0.f, 0.f, 0.f};
        acc = __builtin_amdgcn_mfma_f32_16x16x32_f16(ah[0], bh0, acc, 0, 0, 0);
        acc = __builtin_amdgcn_mfma_f32_16x16x32_f16(ah[1], bh1, acc, 0, 0, 0);
        acc = __builtin_amdgcn_mfma_f32_16x16x32_f16(ah[0], bl0, acc, 0, 0, 0);
        acc = __builtin_amdgcn_mfma_f32_16x16x32_f16(ah[1], bl1, acc, 0, 0, 0);
        acc = __builtin_amdgcn_mfma_f32_16x16x32_f16(al[0], bh0, acc, 0, 0, 0);
        acc = __builtin_amdgcn_mfma_f32_16x16x32_f16(al[1], bh1, acc, 0, 0, 0);
        #pragma unroll
        for (int r = 0; r < 4; r++)
            s_g[gg][rt * 16 + kg * 4 + r][ct * 16 + r16] = acc[r];
    }
    __syncthreads();

    int node = t >> 3;
    int f0 = (t & 7) * 8;
    int n2 = base + node;
    #pragma unroll
    for (int j = 0; j < 8; j++){
        int f = f0 + j;
        float gir = s_g[0][node][f]       + effb[f];
        float giz = s_g[0][node][64 + f]  + effb[64 + f];
        float gin = s_g[0][node][128 + f] + effb[128 + f];
        float ghr = s_g[1][node][f]       + bhh[f];
        float ghz = s_g[1][node][64 + f]  + bhh[64 + f];
        float ghn = s_g[1][node][128 + f] + bhh[128 + f];
        float r = sigmoidf_(gir + ghr);
        float z = sigmoidf_(giz + ghz);
        float nv = tanhf_(gin + r * ghn);
        size_t hb = (size_t)n2 * 64 + f;
        float hv = h[hb];
        h[hb] = (1.f - z) * nv + z * hv;
        m[hb] = 0.f;                         // re-zero for next step's atomics
    }
}

// ---------------- Set2Set + final projection: one block per graph ------------
// Attention rewritten as ONE online-softmax pass (flash-style): 16 groups x
// 16 lanes x f32x4 -- 16 nodes in flight, 4-shuffle reduce (vs 2 passes,
// 4 nodes, 6 shuffles, e_ws global round-trip in R20's 161us version).
__global__ __launch_bounds__(256) void set2set_kernel(
    const float* __restrict__ out, const int* __restrict__ offs,
    const float* __restrict__ lsT, const float* __restrict__ ls_bih,
    const float* __restrict__ ls_bhh, const float* __restrict__ lin3T,
    const float* __restrict__ lin3_b, const float* __restrict__ pred_w,
    const float* __restrict__ pred_b, float* __restrict__ pred_out)
{
    int g = blockIdx.x;
    int t = threadIdx.x;
    __shared__ float s_qstar[128], s_h[3][64], s_c[3][64], s_g[256], s_y[128];
    __shared__ float s_gm[16], s_gw[16];
    __shared__ float s_gr[16][68];
    if (t < 128) s_qstar[t] = 0.f;
    if (t < 192){ s_h[t / 64][t % 64] = 0.f; s_c[t / 64][t % 64] = 0.f; }
    int ns = offs[g], ne = offs[g + 1];
    const int lg = t >> 4;                   // group 0..15
    const int li = t & 15;                   // lane in group
    __syncthreads();

#define LSTM_GATE(L)                                                         \
    __syncthreads();                                                         \
    s_g[t] = acc;                                                            \
    __syncthreads();                                                         \
    if (t < 64){                                                             \
        float iv = s_g[t], fv = s_g[64 + t], gv = s_g[128 + t], ov = s_g[192 + t]; \
        float c2 = sigmoidf_(fv) * s_c[L][t] + sigmoidf_(iv) * tanhf_(gv);   \
        float h2 = sigmoidf_(ov) * tanhf_(c2);                               \
        s_c[L][t] = c2; s_h[L][t] = h2;                                      \
    }                                                                        \
    __syncthreads();

    for (int it = 0; it < 6; it++){
        {   // layer 0: x = q_star (128)
            float acc = ls_bih[t] + ls_bhh[t];
            const float* wx = lsT;                       // [128][256]
            #pragma unroll 32
            for (int j = 0; j < 128; j++) acc = fmaf(s_qstar[j], wx[j * 256 + t], acc);
            const float* wh = lsT + 65536;               // whh[0]: [64][256]
            #pragma unroll 32
            for (int j = 0; j < 64; j++) acc = fmaf(s_h[0][j], wh[j * 256 + t], acc);
            LSTM_GATE(0)
        }
        {   // layer 1: x = h0 (64)
            float acc = ls_bih[256 + t] + ls_bhh[256 + t];
            const float* wx = lsT + 32768;               // wih12[0]: [64][256]
            #pragma unroll 32
            for (int j = 0; j < 64; j++) acc = fmaf(s_h[0][j], wx[j * 256 + t], acc);
            const float* wh = lsT + 65536 + 16384;       // whh[1]
            #pragma unroll 32
            for (int j = 0; j < 64; j++) acc = fmaf(s_h[1][j], wh[j * 256 + t], acc);
            LSTM_GATE(1)
        }
        {   // layer 2: x = h1 (64)
            float acc = ls_bih[512 + t] + ls_bhh[512 + t];
            const float* wx = lsT + 32768 + 16384;       // wih12[1]
            #pragma unroll 32
            for (int j = 0; j < 64; j++) acc = fmaf(s_h[1][j], wx[j * 256 + t], acc);
            const float* wh = lsT + 65536 + 2 * 16384;   // whh[2]
            #pragma unroll 32
            for (int j = 0; j < 64; j++) acc = fmaf(s_h[2][j], wh[j * 256 + t], acc);
            LSTM_GATE(2)
        }
        // ---- online-softmax attention: q = s_h[2] ----
        f32x4 qv = *(const f32x4*)&s_h[2][li * 4];
        f32x4 racc = {0.f, 0.f, 0.f, 0.f};
        float mrun = -3.4e38f, wsum = 0.f;
        for (int n = ns + lg; n < ne; n += 16){
            f32x4 ov = *(const f32x4*)&out[(size_t)n * 64 + li * 4];
            float p = ov[0] * qv[0] + ov[1] * qv[1] + ov[2] * qv[2] + ov[3] * qv[3];
            p += __shfl_xor(p, 1);
            p += __shfl_xor(p, 2);
            p += __shfl_xor(p, 4);
            p += __shfl_xor(p, 8);
            float mn = fmaxf(mrun, p);
            float sc = __expf(mrun - mn);    // -3.4e38 - finite -> 0 (no NaN)
            float w = __expf(p - mn);
            wsum = fmaf(wsum, sc, w);
            racc = racc * sc + ov * w;
            mrun = mn;
        }
        if (li == 0){ s_gm[lg] = mrun; s_gw[lg] = wsum; }
        *(f32x4*)&s_gr[lg][li * 4] = racc;
        __syncthreads();
        if (t < 64){
            float gmax = -3.4e38f;
            #pragma unroll
            for (int g2 = 0; g2 < 16; g2++) gmax = fmaxf(gmax, s_gm[g2]);
            float gsum = 0.f, ro = 0.f;
            #pragma unroll
            for (int g2 = 0; g2 < 16; g2++){
                float e = __expf(s_gm[g2] - gmax);   // (-inf-sentinel)-(-inf)=0 -> e=1 x wsum=0 -> 0
                gsum = fmaf(s_gw[g2], e, gsum);
                ro = fmaf(s_gr[g2][t], e, ro);
            }
            ro = (gsum > 0.f) ? ro / gsum : 0.f;
            s_qstar[t] = s_h[2][t];
            s_qstar[64 + t] = ro;
        }
        __syncthreads();
    }
#undef LSTM_GATE
    if (t < 128){
        float acc = lin3_b[t];
        #pragma unroll 32
        for (int i = 0; i < 128; i++) acc = fmaf(s_qstar[i], lin3T[i * 128 + t], acc);
        s_y[t] = fmaxf(acc, 0.f);
    }
    __syncthreads();
    if (t < 64){
        float p = s_y[t] * pred_w[t] + s_y[64 + t] * pred_w[64 + t];
        #pragma unroll
        for (int o = 1; o < 64; o <<= 1) p += __shfl_xor(p, o);
        if (t == 0) pred_out[g] = p + pred_b[0];
    }
}

extern "C" void kernel_launch(void* const* d_in, const int* in_sizes, int n_in,
                              void* d_out, int out_size, void* d_ws, size_t ws_size,
                              hipStream_t stream)
{
    (void)in_sizes; (void)n_in; (void)out_size; (void)ws_size;
    const float* n_feat  = (const float*)d_in[0];
    const float* e_feat  = (const float*)d_in[1];
    const int*   src     = (const int*)d_in[2];
    const int*   dst     = (const int*)d_in[3];
    const int*   node_graph = (const int*)d_in[4];
    const float* lin0_w  = (const float*)d_in[6];
    const float* lin0_b  = (const float*)d_in[7];
    const float* en_w1   = (const float*)d_in[8];
    const float* en_b1   = (const float*)d_in[9];
    const float* en_w2   = (const float*)d_in[10];
    const float* en_b2   = (const float*)d_in[11];
    const float* conv_b  = (const float*)d_in[12];
    const float* gru_wih = (const float*)d_in[13];
    const float* gru_whh = (const float*)d_in[14];
    const float* gru_bih = (const float*)d_in[15];
    const float* gru_bhh = (const float*)d_in[16];
    const float* ls_wih0 = (const float*)d_in[17];
    const float* ls_wih12= (const float*)d_in[18];
    const float* ls_whh  = (const float*)d_in[19];
    const float* ls_bih  = (const float*)d_in[20];
    const float* ls_bhh  = (const float*)d_in[21];
    const float* lin3_w  = (const float*)d_in[22];
    const float* lin3_b  = (const float*)d_in[23];
    const float* pred_w  = (const float*)d_in[24];
    const float* pred_b  = (const float*)d_in[25];

    float* h = (float*)d_out;                       // N x 64 (also "out")
    float* pred_out = (float*)d_out + (size_t)NN * 64;

    char* ws = (char*)d_ws;
    f16*   hidh  = (f16*)(ws + 0);                  // 25,600,000
    float* m     = (float*)(ws + 25600000);         // 10,240,000
    f16*   w2h   = (f16*)(ws + 35840000);           //  1,048,576
    f16*   wf16h = (f16*)(ws + 36888576);           //     49,152
    f16*   wf16l = (f16*)(ws + 36937728);           //     49,152
    float* lsT   = (float*)(ws + 36986880);         //    458,752
    float* lin3T = (float*)(ws + 37445632);         //     65,536
    float* effb  = (float*)(ws + 37511168);         //        768
    int*   offs  = (int*)(ws + 37511936);           //      1,028

    prep_kernel<<<2754, 256, 0, stream>>>(en_w2, w2h, gru_wih, gru_whh,
                                          wf16h, wf16l,
                                          ls_wih0, ls_wih12, ls_whh, lsT,
                                          lin3_w, lin3T, gru_bih, conv_b, effb,
                                          node_graph, offs);
    lin0_kernel<<<(NN * 64) / 256, 256, 0, stream>>>(n_feat, lin0_w, lin0_b, h);
    edge_hidden_kernel<<<(EE * 128) / 256, 256, 0, stream>>>(e_feat, en_w1, en_b1, hidh);
    hipMemsetAsync(m, 0, (size_t)NN * 64 * sizeof(float), stream);

    for (int step = 0; step < 6; step++){
        msg_fused_kernel<<<(EE + EPB - 1) / EPB, 512, 0, stream>>>(h, hidh, w2h,
                                                                   en_b2, src, dst, m);
        gru_mfma_kernel<<<NN / 32, 256, 0, stream>>>(m, h, wf16h, wf16l, effb, gru_bhh);
    }

    set2set_kernel<<<BB, 256, 0, stream>>>(h, offs, lsT, ls_bih, ls_bhh,
                                           lin3T, lin3_b, pred_w, pred_b,
                                           pred_out);
}